// Round 4
// baseline (7174.301 us; speedup 1.0000x reference)
//
#include <hip/hip_runtime.h>
#include <hip/hip_bf16.h>
#include <stdint.h>

#define EDIM 300
#define KP   320      // padded E for MFMA K-loop
#define HDIM 256
#define G4H  1024
#define NB   2048     // both directions' gates
#define TAGS 9
#define BATCH 64
#define SEQ  512
#define MROWS (SEQ*BATCH)   // 32768

typedef _Float16 f16;
typedef _Float16 half2_t __attribute__((ext_vector_type(2)));
typedef _Float16 half8_t __attribute__((ext_vector_type(8)));
typedef float    floatx4 __attribute__((ext_vector_type(4)));
typedef uint32_t u32x4   __attribute__((ext_vector_type(4)));

__device__ __forceinline__ float fast_sigmoid(float x) {
    return __builtin_amdgcn_rcpf(1.f + __expf(-x));
}
__device__ __forceinline__ float fast_tanh(float x) {
    // 1 - 2/(e^{2x}+1); exact at +-inf via rcp(inf)=0
    return 1.f - 2.f*__builtin_amdgcn_rcpf(__expf(2.f*x) + 1.f);
}

// ---- pack input-projection weights [n<1024: wih_f | n>=1024: wih_b], K padded to 320, + fused bias
__global__ void k_pack_wih(const float* __restrict__ wih_f, const float* __restrict__ wih_b,
                           const float* __restrict__ bih_f, const float* __restrict__ bhh_f,
                           const float* __restrict__ bih_b, const float* __restrict__ bhh_b,
                           f16* __restrict__ wpack, float* __restrict__ bias2) {
    int n = blockIdx.x;
    const float* src = (n < G4H) ? (wih_f + (long)n*EDIM) : (wih_b + (long)(n-G4H)*EDIM);
    for (int k = threadIdx.x; k < KP; k += 64)
        wpack[(long)n*KP + k] = (k < EDIM) ? (f16)src[k] : (f16)0.f;
    if (threadIdx.x == 0)
        bias2[n] = (n < G4H) ? (bih_f[n] + bhh_f[n]) : (bih_b[n-G4H] + bhh_b[n-G4H]);
}

// ---- pack recurrent weights into MFMA A-fragment layout (validated R2/R3):
// frag index = ((dir*8 + w)*8 + fr)*8 + kf ; per frag 64 lanes x 8 f16.
// A[row][k]: row = lane&15, k = (lane>>4)*8 + j.
// gate row = (fr>>1)*256 + w*32 + (fr&1)*16 + (lane&15); k = kf*32 + (lane>>4)*8 + j.
__global__ void k_pack_whh2(const float* __restrict__ whh_f, const float* __restrict__ whh_b,
                            f16* __restrict__ whhp2) {
    int idx = blockIdx.x*256 + threadIdx.x;   // 65536 = 2*8*8*8*64
    int lane = idx & 63;
    int kf = (idx >> 6) & 7;
    int fr = (idx >> 9) & 7;
    int w  = (idx >> 12) & 7;
    int dir = idx >> 15;
    const float* whh = dir ? whh_b : whh_f;
    int grow = (fr >> 1)*256 + w*32 + (fr & 1)*16 + (lane & 15);
    int k0 = kf*32 + (lane >> 4)*8;
    const float* src = whh + (long)grow*HDIM + k0;
    f16 tmp[8];
    #pragma unroll
    for (int j = 0; j < 8; ++j) tmp[j] = (f16)src[j];
    *(uint4*)(whhp2 + (size_t)idx*8) = *(uint4*)tmp;
}

// ---- embedding gather, f16, row m = t*64+b, padded to KP
__global__ void k_gather(const int* __restrict__ sentence, const float* __restrict__ embed,
                         f16* __restrict__ xg) {
    int m = blockIdx.x;
    int t = m >> 6, b = m & 63;
    int tok = sentence[b*SEQ + t];
    const float* row = embed + (long)tok*EDIM;
    for (int e = threadIdx.x; e < KP; e += 64)
        xg[(long)m*KP + e] = (e < EDIM) ? (f16)row[e] : (f16)0.f;
}

// ---- xp4 GEMM, M=32768 N=2048 K=320; epilogue writes x-preacts directly in the
// fragment order k_recur consumes:
// xp4[ ((dir*64 + b)*512 + s)*1024 + row' ],  row' = wv*128 + fr*16 + rho,
// fr = gate*2 + half, s = dir ? SEQ-1-t : t.
__launch_bounds__(256)
__global__ void k_gemm_xproj(const f16* __restrict__ xg, const f16* __restrict__ wpack,
                             const float* __restrict__ bias2, f16* __restrict__ xp4) {
    __shared__ __align__(16) f16 As[128*40];
    __shared__ __align__(16) f16 Bs[128*40];
    int tid = threadIdx.x;
    int bm = blockIdx.x, bn = blockIdx.y;
    int wid = tid >> 6, lane = tid & 63;
    int waveM = wid & 1, waveN = wid >> 1;
    int quad = lane >> 4, mlo = lane & 15;
    floatx4 acc[4][4] = {};
    for (int k0 = 0; k0 < KP; k0 += 32) {
        for (int it = 0; it < 2; ++it) {
            int c = tid + it*256;
            int row = c >> 2, ko = (c & 3)*8;
            *(uint4*)(&As[row*40 + ko]) = *(const uint4*)(&xg[(long)(bm*128+row)*KP + k0 + ko]);
            *(uint4*)(&Bs[row*40 + ko]) = *(const uint4*)(&wpack[(long)(bn*128+row)*KP + k0 + ko]);
        }
        __syncthreads();
        half8_t af[4], bf[4];
        #pragma unroll
        for (int i = 0; i < 4; ++i)
            af[i] = *(const half8_t*)(&As[(waveM*64 + i*16 + mlo)*40 + quad*8]);
        #pragma unroll
        for (int j = 0; j < 4; ++j)
            bf[j] = *(const half8_t*)(&Bs[(waveN*64 + j*16 + mlo)*40 + quad*8]);
        #pragma unroll
        for (int i = 0; i < 4; ++i)
            #pragma unroll
            for (int j = 0; j < 4; ++j)
                acc[i][j] = __builtin_amdgcn_mfma_f32_16x16x32_f16(af[i], bf[j], acc[i][j], 0, 0, 0);
        __syncthreads();
    }
    #pragma unroll
    for (int i = 0; i < 4; ++i)
        #pragma unroll
        for (int j = 0; j < 4; ++j) {
            int col = bn*128 + waveN*64 + j*16 + mlo;   // 0..2047
            float bv = bias2[col];
            int dir = col >> 10, grow = col & 1023;
            int g = grow >> 8, wv = (grow >> 5) & 7, hf = (grow >> 4) & 1, rho = grow & 15;
            int rowp = wv*128 + (g*2 + hf)*16 + rho;
            #pragma unroll
            for (int r = 0; r < 4; ++r) {
                int row = bm*128 + waveM*64 + i*16 + quad*4 + r;
                int t = row >> 6, bb = row & 63;
                int s = dir ? (SEQ-1-t) : t;
                xp4[((size_t)(dir*64 + bb)*512 + s)*1024 + rowp] = (f16)(acc[i][j][r] + bv);
            }
        }
}

// ---- LSTM recurrence on MFMA, one WG per (dir,batch): 128 WGs, 512 threads = 8 waves.
// Per step: gates[1024] = Whh @ h via 64 mfma_16x16x32_f16 per wave. Wave w owns
// gate rows g*256 + w*32 + half*16 + row -> lane-local cell update (validated R3).
// W: 46/64 frags per wave PINNED IN AGPRs (MFMA reads AGPR natively; in-loop "+a"
// asm forbids scratch demotion), 18 frags in LDS (144 KB, the LDS capacity limit).
// x-preacts: per-lane global uint2 loads from xp4 fragment layout, prefetched one
// step ahead (no LDS roundtrip). Raw lgkmcnt+s_barrier per step keeps global
// loads in flight. h history flushed to hcat coalesced once per 8 steps.
#define WFREG 46
#define WFLDS 18
__launch_bounds__(512, 2)
__global__ void k_recur(const f16* __restrict__ xp4, const f16* __restrict__ whhp2,
                        f16* __restrict__ hcat) {
    __shared__ __align__(16) uint4 ldsW[8*WFLDS*64];   // 144 KB
    __shared__ __align__(16) f16 hbuf[2][264];         // 1056 B (528B rows, 16B-aligned)
    __shared__ __align__(16) f16 hist[2][8][256];      // 8 KB
    int dir = blockIdx.x & 1, b = blockIdx.x >> 1;
    int tid = threadIdx.x, w = tid >> 6, lane = tid & 63;
    int q = lane >> 4;

    // stationary weight fragments
    const f16* wbase = whhp2 + (size_t)(dir*8 + w)*32768;
    u32x4 wreg[WFREG];
    #pragma unroll
    for (int f = 0; f < WFREG; ++f)
        wreg[f] = *(const u32x4*)(wbase + ((size_t)f*64 + lane)*8);
    #pragma unroll
    for (int f = WFREG; f < 64; ++f)
        ldsW[(w*WFLDS + (f-WFREG))*64 + lane] =
            *(const uint4*)(wbase + ((size_t)f*64 + lane)*8);

    if (tid < 132) ((uint32_t*)&hbuf[0][0])[tid] = 0u;

    // per-lane x source in xp4 fragment order (f16 units)
    const f16* xs = xp4 + ((size_t)(dir*64 + b)*512)*1024 + w*128 + q*4;
    uint2 xw[8];
    #pragma unroll
    for (int fr = 0; fr < 8; ++fr) xw[fr] = *(const uint2*)(xs + fr*16);

    float cst[8] = {};
    __syncthreads();

    for (int blk = 0; blk < 64; ++blk) {
        int hb2 = blk & 1;
        for (int k = 0; k < 8; ++k) {
            int s = blk*8 + k;
            int cur = s & 1, nxt = cur ^ 1;
            // pin W fragments into AGPRs through the loop body
            #pragma unroll
            for (int f = 0; f < WFREG; ++f) asm volatile("" : "+a"(wreg[f]));
            // C-init = x preacts (lane-local from prefetched regs)
            floatx4 acc[8];
            #pragma unroll
            for (int fr = 0; fr < 8; ++fr) {
                half2_t x01 = __builtin_bit_cast(half2_t, xw[fr].x);
                half2_t x23 = __builtin_bit_cast(half2_t, xw[fr].y);
                acc[fr][0] = (float)x01[0]; acc[fr][1] = (float)x01[1];
                acc[fr][2] = (float)x23[0]; acc[fr][3] = (float)x23[1];
            }
            // prefetch next step's x (stays in flight across raw barriers)
            {
                int sp = (s+1 < SEQ) ? s+1 : s;
                const f16* xn = xs + (size_t)sp*1024;
                #pragma unroll
                for (int fr = 0; fr < 8; ++fr) xw[fr] = *(const uint2*)(xn + fr*16);
            }
            // MFMA over K=256
            const f16* hp = &hbuf[cur][0];
            #pragma unroll
            for (int kf = 0; kf < 8; ++kf) {
                half8_t bf = *(const half8_t*)(hp + kf*32 + q*8);
                #pragma unroll
                for (int fr = 0; fr < 8; ++fr) {
                    int f = fr*8 + kf;
                    half8_t af;
                    if (f < WFREG) af = __builtin_bit_cast(half8_t, wreg[f]);
                    else af = *(const half8_t*)((const f16*)&ldsW[(w*WFLDS + (f-WFREG))*64 + lane]);
                    acc[fr] = __builtin_amdgcn_mfma_f32_16x16x32_f16(af, bf, acc[fr], 0, 0, 0);
                }
            }
            // lane-local LSTM cell (all lanes compute; only col-0 lanes write)
            float hv[8];
            #pragma unroll
            for (int hf = 0; hf < 2; ++hf)
                #pragma unroll
                for (int r = 0; r < 4; ++r) {
                    int ui = hf*4 + r;
                    float si = fast_sigmoid(acc[0+hf][r]);
                    float sf = fast_sigmoid(acc[2+hf][r]);
                    float tg = fast_tanh(acc[4+hf][r]);
                    float so = fast_sigmoid(acc[6+hf][r]);
                    cst[ui] = __builtin_fmaf(sf, cst[ui], si*tg);
                    hv[ui] = so * fast_tanh(cst[ui]);
                }
            if ((lane & 15) == 0) {
                #pragma unroll
                for (int hf = 0; hf < 2; ++hf) {
                    half2_t p01, p23;
                    p01[0] = (f16)hv[hf*4+0]; p01[1] = (f16)hv[hf*4+1];
                    p23[0] = (f16)hv[hf*4+2]; p23[1] = (f16)hv[hf*4+3];
                    uint2 pk;
                    pk.x = __builtin_bit_cast(uint32_t, p01);
                    pk.y = __builtin_bit_cast(uint32_t, p23);
                    int u = w*32 + hf*16 + q*4;
                    *(uint2*)&hbuf[nxt][u] = pk;
                    *(uint2*)&hist[hb2][k][u] = pk;
                }
            }
            asm volatile("s_waitcnt lgkmcnt(0)" ::: "memory");
            __builtin_amdgcn_s_barrier();
            asm volatile("" ::: "memory");
        }
        // coalesced hcat flush of the finished 8-step block
        {
            int kk = tid >> 6, u0 = (tid & 63)*4;
            int sF = blk*8 + kk;
            int tF = dir ? (SEQ-1-sF) : sF;
            uint2 v = *(const uint2*)&hist[hb2][kk][u0];
            *(uint2*)(hcat + ((size_t)tF*64 + b)*512 + dir*HDIM + u0) = v;
        }
    }
}

// ---- emissions: one wave per (t,b) row; lanes split K=512; 9 shuffle-reduced dots
__launch_bounds__(256)
__global__ void k_emis(const f16* __restrict__ hcat, const float* __restrict__ w_out,
                       const float* __restrict__ b_out, float* __restrict__ emis) {
    int r = blockIdx.x*4 + (threadIdx.x >> 6);
    int lane = threadIdx.x & 63;
    float hv[8];
    #pragma unroll
    for (int i = 0; i < 8; ++i) hv[i] = (float)hcat[(long)r*512 + lane + i*64];
    for (int tag = 0; tag < TAGS; ++tag) {
        float acc = 0.f;
        #pragma unroll
        for (int i = 0; i < 8; ++i) acc += hv[i]*w_out[tag*512 + lane + i*64];
        for (int off = 32; off; off >>= 1) acc += __shfl_xor(acc, off);
        if (lane == 0) emis[(long)r*TAGS + tag] = acc + b_out[tag];
    }
}

// ---- CRF: one wave per batch row. Gold score (lane-parallel over t) + forward logZ
__launch_bounds__(256)
__global__ void k_crf(const float* __restrict__ emis, const int* __restrict__ tags,
                      const int* __restrict__ mask, const float* __restrict__ start_trans,
                      const float* __restrict__ end_trans, const float* __restrict__ trans,
                      float* __restrict__ out) {
    int b = blockIdx.x*4 + (threadIdx.x >> 6);
    int lane = threadIdx.x & 63;
    int len = 0;
    #pragma unroll
    for (int i = 0; i < 8; ++i) len += mask[b*SEQ + lane + i*64];
    for (int off = 32; off; off >>= 1) len += __shfl_xor(len, off);
    float sc = 0.f;
    for (int i = 0; i < 8; ++i) {
        int t = 1 + lane + i*64;
        if (t < SEQ && mask[b*SEQ + t]) {
            int tp = tags[b*SEQ + t - 1], tc = tags[b*SEQ + t];
            sc += trans[tp*TAGS + tc] + emis[(long)(t*64 + b)*TAGS + tc];
        }
    }
    for (int off = 32; off; off >>= 1) sc += __shfl_xor(sc, off);
    int tag0 = tags[b*SEQ];
    sc += start_trans[tag0] + emis[(long)b*TAGS + tag0];
    sc += end_trans[tags[b*SEQ + len - 1]];
    bool act = lane < TAGS;
    int j = act ? lane : 0;
    float tcol[TAGS];
    #pragma unroll
    for (int i = 0; i < TAGS; ++i) tcol[i] = trans[i*TAGS + j];
    float alpha = act ? (start_trans[j] + emis[(long)b*TAGS + j]) : -1e30f;
    for (int t = 1; t < SEQ; ++t) {
        int mt = mask[b*SEQ + t];
        float em = emis[(long)(t*64 + b)*TAGS + j];
        float v[TAGS], mx = -1e30f;
        #pragma unroll
        for (int i = 0; i < TAGS; ++i) { v[i] = __shfl(alpha, i) + tcol[i]; mx = fmaxf(mx, v[i]); }
        float ss = 0.f;
        #pragma unroll
        for (int i = 0; i < TAGS; ++i) ss += __expf(v[i] - mx);
        float nxt = mx + __logf(ss) + em;
        if (mt && act) alpha = nxt;
    }
    float fv = act ? (alpha + end_trans[j]) : -1e30f;
    float mx = fv;
    for (int off = 32; off; off >>= 1) mx = fmaxf(mx, __shfl_xor(mx, off));
    float ss = act ? __expf(fv - mx) : 0.f;
    for (int off = 32; off; off >>= 1) ss += __shfl_xor(ss, off);
    float logZ = mx + __logf(ss);
    if (lane == 0) atomicAdd(out, (logZ - sc) * (1.0f/BATCH));
}

extern "C" void kernel_launch(void* const* d_in, const int* in_sizes, int n_in,
                              void* d_out, int out_size, void* d_ws, size_t ws_size,
                              hipStream_t stream) {
    const int*   sentence    = (const int*)  d_in[0];
    const int*   tags        = (const int*)  d_in[1];
    const float* embed       = (const float*)d_in[2];
    const float* wih_f       = (const float*)d_in[3];
    const float* whh_f       = (const float*)d_in[4];
    const float* bih_f       = (const float*)d_in[5];
    const float* bhh_f       = (const float*)d_in[6];
    const float* wih_b       = (const float*)d_in[7];
    const float* whh_b       = (const float*)d_in[8];
    const float* bih_b       = (const float*)d_in[9];
    const float* bhh_b       = (const float*)d_in[10];
    const float* w_out       = (const float*)d_in[11];
    const float* b_out       = (const float*)d_in[12];
    const float* start_trans = (const float*)d_in[13];
    const float* end_trans   = (const float*)d_in[14];
    const float* trans       = (const float*)d_in[15];
    const int*   mask        = (const int*)  d_in[16];

    char* ws = (char*)d_ws;
    f16*   xg     = (f16*)ws;   ws += (size_t)MROWS*KP*2;      // 20.97 MB
    f16*   wpack  = (f16*)ws;   ws += (size_t)NB*KP*2;         // 1.31 MB
    float* bias2  = (float*)ws; ws += (size_t)NB*4;            // 8 KB
    f16*   whhp2  = (f16*)ws;   ws += (size_t)1024*512*2;      // 1.05 MB
    f16*   xp4    = (f16*)ws;   ws += (size_t)MROWS*NB*2;      // 134.2 MB
    f16*   hcat   = (f16*)ws;   ws += (size_t)MROWS*512*2;     // 33.55 MB
    float* emis   = (float*)ws; ws += (size_t)MROWS*TAGS*4;    // 1.18 MB

    hipLaunchKernelGGL(k_pack_wih, dim3(NB), dim3(64), 0, stream,
                       wih_f, wih_b, bih_f, bhh_f, bih_b, bhh_b, wpack, bias2);
    hipLaunchKernelGGL(k_pack_whh2, dim3(256), dim3(256), 0, stream, whh_f, whh_b, whhp2);
    hipLaunchKernelGGL(k_gather, dim3(MROWS), dim3(64), 0, stream, sentence, embed, xg);
    hipLaunchKernelGGL(k_gemm_xproj, dim3(256,16), dim3(256), 0, stream, xg, wpack, bias2, xp4);
    hipLaunchKernelGGL(k_recur, dim3(128), dim3(512), 0, stream, xp4, whhp2, hcat);
    hipLaunchKernelGGL(k_emis, dim3(MROWS/4), dim3(256), 0, stream, hcat, w_out, b_out, emis);
    hipMemsetAsync(d_out, 0, sizeof(float), stream);
    hipLaunchKernelGGL(k_crf, dim3(BATCH/4), dim3(256), 0, stream,
                       emis, tags, mask, start_trans, end_trans, trans, (float*)d_out);
}

// Round 5
// 1632.942 us; speedup vs baseline: 4.3935x; 4.3935x over previous
//
#include <hip/hip_runtime.h>
#include <hip/hip_bf16.h>
#include <stdint.h>

#define EDIM 300
#define KP   320      // padded E for MFMA K-loop
#define HDIM 256
#define G4H  1024
#define NB   2048     // both directions' gates
#define TAGS 9
#define BATCH 64
#define SEQ  512
#define MROWS (SEQ*BATCH)   // 32768

typedef _Float16 f16;
typedef _Float16 half2_t __attribute__((ext_vector_type(2)));
typedef _Float16 half8_t __attribute__((ext_vector_type(8)));
typedef float    floatx4 __attribute__((ext_vector_type(4)));
typedef uint32_t u32x4   __attribute__((ext_vector_type(4)));

__device__ __forceinline__ float fast_sigmoid(float x) {
    return __builtin_amdgcn_rcpf(1.f + __expf(-x));
}
__device__ __forceinline__ float fast_tanh(float x) {
    // 1 - 2/(e^{2x}+1); exact at +-inf via rcp(inf)=0
    return 1.f - 2.f*__builtin_amdgcn_rcpf(__expf(2.f*x) + 1.f);
}

// ---- pack input-projection weights [n<1024: wih_f | n>=1024: wih_b], K padded to 320, + fused bias
__global__ void k_pack_wih(const float* __restrict__ wih_f, const float* __restrict__ wih_b,
                           const float* __restrict__ bih_f, const float* __restrict__ bhh_f,
                           const float* __restrict__ bih_b, const float* __restrict__ bhh_b,
                           f16* __restrict__ wpack, float* __restrict__ bias2) {
    int n = blockIdx.x;
    const float* src = (n < G4H) ? (wih_f + (long)n*EDIM) : (wih_b + (long)(n-G4H)*EDIM);
    for (int k = threadIdx.x; k < KP; k += 64)
        wpack[(long)n*KP + k] = (k < EDIM) ? (f16)src[k] : (f16)0.f;
    if (threadIdx.x == 0)
        bias2[n] = (n < G4H) ? (bih_f[n] + bhh_f[n]) : (bih_b[n-G4H] + bhh_b[n-G4H]);
}

// ---- pack recurrent weights into MFMA A-fragment layout for the 4-wave k_recur:
// frag f = ((dir*4 + w)*16 + fr)*8 + kf ; per frag: 64 lanes x 8 f16.
// A[row][k]: row = lane&15, k = (lane>>4)*8 + j.
// gate row = (fr>>2)*256 + w*64 + (fr&3)*16 + (lane&15); k = kf*32 + (lane>>4)*8 + j.
__global__ void k_pack_whh3(const float* __restrict__ whh_f, const float* __restrict__ whh_b,
                            f16* __restrict__ whhp3) {
    int idx = blockIdx.x*256 + threadIdx.x;   // 65536 = 2*4*16*8*64
    int lane = idx & 63;
    int kf = (idx >> 6) & 7;
    int fr = (idx >> 9) & 15;
    int w  = (idx >> 13) & 3;
    int dir = idx >> 15;
    const float* whh = dir ? whh_b : whh_f;
    int grow = (fr >> 2)*256 + w*64 + (fr & 3)*16 + (lane & 15);
    int k0 = kf*32 + (lane >> 4)*8;
    const float* src = whh + (long)grow*HDIM + k0;
    f16 tmp[8];
    #pragma unroll
    for (int j = 0; j < 8; ++j) tmp[j] = (f16)src[j];
    *(uint4*)(whhp3 + (size_t)idx*8) = *(uint4*)tmp;
}

// ---- embedding gather, f16, row m = t*64+b, padded to KP
__global__ void k_gather(const int* __restrict__ sentence, const float* __restrict__ embed,
                         f16* __restrict__ xg) {
    int m = blockIdx.x;
    int t = m >> 6, b = m & 63;
    int tok = sentence[b*SEQ + t];
    const float* row = embed + (long)tok*EDIM;
    for (int e = threadIdx.x; e < KP; e += 64)
        xg[(long)m*KP + e] = (e < EDIM) ? (f16)row[e] : (f16)0.f;
}

// ---- xp5 GEMM, M=32768 N=2048 K=320; epilogue writes x-preacts so that unit u's
// four gates (i,f,g,o) are adjacent:
// xp5[ ((dir*64 + b)*512 + s)*1024 + u*4 + gate ],  s = dir ? SEQ-1-t : t,
// where col = dir*1024 + gate*256 + u (u = 0..255).
__launch_bounds__(256)
__global__ void k_gemm_xproj(const f16* __restrict__ xg, const f16* __restrict__ wpack,
                             const float* __restrict__ bias2, f16* __restrict__ xp5) {
    __shared__ __align__(16) f16 As[128*40];
    __shared__ __align__(16) f16 Bs[128*40];
    int tid = threadIdx.x;
    int bm = blockIdx.x, bn = blockIdx.y;
    int wid = tid >> 6, lane = tid & 63;
    int waveM = wid & 1, waveN = wid >> 1;
    int quad = lane >> 4, mlo = lane & 15;
    floatx4 acc[4][4] = {};
    for (int k0 = 0; k0 < KP; k0 += 32) {
        for (int it = 0; it < 2; ++it) {
            int c = tid + it*256;
            int row = c >> 2, ko = (c & 3)*8;
            *(uint4*)(&As[row*40 + ko]) = *(const uint4*)(&xg[(long)(bm*128+row)*KP + k0 + ko]);
            *(uint4*)(&Bs[row*40 + ko]) = *(const uint4*)(&wpack[(long)(bn*128+row)*KP + k0 + ko]);
        }
        __syncthreads();
        half8_t af[4], bf[4];
        #pragma unroll
        for (int i = 0; i < 4; ++i)
            af[i] = *(const half8_t*)(&As[(waveM*64 + i*16 + mlo)*40 + quad*8]);
        #pragma unroll
        for (int j = 0; j < 4; ++j)
            bf[j] = *(const half8_t*)(&Bs[(waveN*64 + j*16 + mlo)*40 + quad*8]);
        #pragma unroll
        for (int i = 0; i < 4; ++i)
            #pragma unroll
            for (int j = 0; j < 4; ++j)
                acc[i][j] = __builtin_amdgcn_mfma_f32_16x16x32_f16(af[i], bf[j], acc[i][j], 0, 0, 0);
        __syncthreads();
    }
    #pragma unroll
    for (int i = 0; i < 4; ++i)
        #pragma unroll
        for (int j = 0; j < 4; ++j) {
            int col = bn*128 + waveN*64 + j*16 + mlo;   // 0..2047
            float bv = bias2[col];
            int dir = col >> 10, grow = col & 1023;
            int gate = grow >> 8, u = grow & 255;
            int rowp = u*4 + gate;
            #pragma unroll
            for (int r = 0; r < 4; ++r) {
                int row = bm*128 + waveM*64 + i*16 + quad*4 + r;
                int t = row >> 6, bb = row & 63;
                int s = dir ? (SEQ-1-t) : t;
                xp5[((size_t)(dir*64 + bb)*512 + s)*1024 + rowp] = (f16)(acc[i][j][r] + bv);
            }
        }
}

// ---- LSTM recurrence on MFMA, one WG per (dir,batch): 128 WGs, 256 threads = 4 waves,
// 1 wave/SIMD, __launch_bounds__(256,1) -> 512-reg/wave budget. Wave w owns gate rows
// {gate*256 + w*64 .. +64} for all 4 gates (16 frags x 8 kf = 128 MFMA/step/wave).
// W: 96 frags/wave in registers (384 regs; AGPR+VGPR, MFMA reads both natively),
// 32 frags/wave in LDS (128 KB total). Cell phase: col-0 lanes dump acc to a 4KB
// wave-local gbuf (no barrier needed), then each of the 64 lanes updates exactly one
// unit. x-preacts: one coalesced uint2/lane/step from xp5 (gates adjacent),
// prefetched one step ahead. One raw lgkmcnt(0)+s_barrier per step (no vmcnt drain).
// h: double-buffered 256-f16 hbuf + direct contiguous 128B/wave hcat store.
#define RFRAG 96
#define LFRAG 32
__launch_bounds__(256, 1)
__global__ void k_recur(const f16* __restrict__ xp5, const f16* __restrict__ whhp3,
                        f16* __restrict__ hcat) {
    __shared__ __align__(16) uint4 ldsW[4*LFRAG*64];   // 128 KB: [w][f-96][lane]
    __shared__ __align__(16) float gbuf[4][16][16];    // 4 KB: [w][fr][lq*4+r] (col 0)
    __shared__ __align__(16) f16 hbuf[2][256];         // 1 KB, double buffered
    int dir = blockIdx.x & 1, b = blockIdx.x >> 1;
    int tid = threadIdx.x, w = tid >> 6, lane = tid & 63;
    int q = lane >> 4;          // k-group / row-quad
    int v = lane;               // unit owned in cell phase: u256 = w*64 + v

    // ---- stationary W fragments (frags 0..95 -> regs, 96..127 -> LDS)
    const f16* wbase = whhp3 + (size_t)(dir*4 + w)*131072;
    u32x4 wreg[RFRAG];
    #pragma unroll
    for (int f = 0; f < RFRAG; ++f)
        wreg[f] = *(const u32x4*)(wbase + ((size_t)f*64 + lane)*8);
    #pragma unroll
    for (int f2 = 0; f2 < LFRAG; ++f2)
        ldsW[(w*LFRAG + f2)*64 + lane] =
            *(const uint4*)(wbase + ((size_t)(RFRAG + f2)*64 + lane)*8);

    if (tid < 128) ((uint32_t*)&hbuf[0][0])[tid] = 0u;

    // per-lane x source: 4 gate preacts of unit (w*64+v), linear in s
    const f16* xs = xp5 + ((size_t)(dir*64 + b)*512)*1024 + (w*64 + v)*4;
    uint2 xw = *(const uint2*)xs;

    float cc = 0.f;
    __syncthreads();

    for (int s = 0; s < SEQ; ++s) {
        int t = dir ? (SEQ-1-s) : s;
        // prefetch next step's x (stays in flight across the raw barrier)
        int sp = (s+1 < SEQ) ? s+1 : s;
        uint2 xn = *(const uint2*)(xs + (size_t)sp*1024);
        // ---- 128 MFMA over K=256 (kf=0 uses C=0: no acc zero-init pass)
        floatx4 acc[16];
        const f16* hp = &hbuf[s & 1][0];
        #pragma unroll
        for (int kf = 0; kf < 8; ++kf) {
            half8_t bf = *(const half8_t*)(hp + kf*32 + q*8);
            #pragma unroll
            for (int fr = 0; fr < 16; ++fr) {
                int f = fr*8 + kf;
                half8_t af;
                if (f < RFRAG) af = __builtin_bit_cast(half8_t, wreg[f]);
                else af = *(const half8_t*)((const f16*)&ldsW[(w*LFRAG + (f-RFRAG))*64 + lane]);
                if (kf == 0)
                    acc[fr] = __builtin_amdgcn_mfma_f32_16x16x32_f16(af, bf, (floatx4){0.f,0.f,0.f,0.f}, 0, 0, 0);
                else
                    acc[fr] = __builtin_amdgcn_mfma_f32_16x16x32_f16(af, bf, acc[fr], 0, 0, 0);
            }
        }
        // ---- col-0 lanes dump gates to wave-local gbuf (no cross-wave use -> no barrier)
        if ((lane & 15) == 0) {
            #pragma unroll
            for (int fr = 0; fr < 16; ++fr)
                *(floatx4*)&gbuf[w][fr][q*4] = acc[fr];
        }
        // ---- each lane updates one unit: u256 = w*64 + v
        {
            int sub = v >> 4, rr = v & 15;
            half2_t xif = __builtin_bit_cast(half2_t, xw.x);
            half2_t xgo = __builtin_bit_cast(half2_t, xw.y);
            float pi = gbuf[w][0  + sub][rr] + (float)xif[0];
            float pf = gbuf[w][4  + sub][rr] + (float)xif[1];
            float pg = gbuf[w][8  + sub][rr] + (float)xgo[0];
            float po = gbuf[w][12 + sub][rr] + (float)xgo[1];
            float si = fast_sigmoid(pi), sf = fast_sigmoid(pf);
            float tg = fast_tanh(pg),   so = fast_sigmoid(po);
            cc = __builtin_fmaf(sf, cc, si*tg);
            f16 hh = (f16)(so * fast_tanh(cc));
            hbuf[(s+1) & 1][w*64 + v] = hh;
            hcat[((size_t)t*64 + b)*512 + dir*HDIM + w*64 + v] = hh;
        }
        xw = xn;
        asm volatile("s_waitcnt lgkmcnt(0)" ::: "memory");
        __builtin_amdgcn_s_barrier();
        asm volatile("" ::: "memory");
    }
}

// ---- emissions: one wave per (t,b) row; lanes split K=512; 9 shuffle-reduced dots
__launch_bounds__(256)
__global__ void k_emis(const f16* __restrict__ hcat, const float* __restrict__ w_out,
                       const float* __restrict__ b_out, float* __restrict__ emis) {
    int r = blockIdx.x*4 + (threadIdx.x >> 6);
    int lane = threadIdx.x & 63;
    float hv[8];
    #pragma unroll
    for (int i = 0; i < 8; ++i) hv[i] = (float)hcat[(long)r*512 + lane + i*64];
    for (int tag = 0; tag < TAGS; ++tag) {
        float acc = 0.f;
        #pragma unroll
        for (int i = 0; i < 8; ++i) acc += hv[i]*w_out[tag*512 + lane + i*64];
        for (int off = 32; off; off >>= 1) acc += __shfl_xor(acc, off);
        if (lane == 0) emis[(long)r*TAGS + tag] = acc + b_out[tag];
    }
}

// ---- CRF: one wave per batch row. Gold score (lane-parallel over t) + forward logZ
__launch_bounds__(256)
__global__ void k_crf(const float* __restrict__ emis, const int* __restrict__ tags,
                      const int* __restrict__ mask, const float* __restrict__ start_trans,
                      const float* __restrict__ end_trans, const float* __restrict__ trans,
                      float* __restrict__ out) {
    int b = blockIdx.x*4 + (threadIdx.x >> 6);
    int lane = threadIdx.x & 63;
    int len = 0;
    #pragma unroll
    for (int i = 0; i < 8; ++i) len += mask[b*SEQ + lane + i*64];
    for (int off = 32; off; off >>= 1) len += __shfl_xor(len, off);
    float sc = 0.f;
    for (int i = 0; i < 8; ++i) {
        int t = 1 + lane + i*64;
        if (t < SEQ && mask[b*SEQ + t]) {
            int tp = tags[b*SEQ + t - 1], tc = tags[b*SEQ + t];
            sc += trans[tp*TAGS + tc] + emis[(long)(t*64 + b)*TAGS + tc];
        }
    }
    for (int off = 32; off; off >>= 1) sc += __shfl_xor(sc, off);
    int tag0 = tags[b*SEQ];
    sc += start_trans[tag0] + emis[(long)b*TAGS + tag0];
    sc += end_trans[tags[b*SEQ + len - 1]];
    bool act = lane < TAGS;
    int j = act ? lane : 0;
    float tcol[TAGS];
    #pragma unroll
    for (int i = 0; i < TAGS; ++i) tcol[i] = trans[i*TAGS + j];
    float alpha = act ? (start_trans[j] + emis[(long)b*TAGS + j]) : -1e30f;
    for (int t = 1; t < SEQ; ++t) {
        int mt = mask[b*SEQ + t];
        float em = emis[(long)(t*64 + b)*TAGS + j];
        float v[TAGS], mx = -1e30f;
        #pragma unroll
        for (int i = 0; i < TAGS; ++i) { v[i] = __shfl(alpha, i) + tcol[i]; mx = fmaxf(mx, v[i]); }
        float ss = 0.f;
        #pragma unroll
        for (int i = 0; i < TAGS; ++i) ss += __expf(v[i] - mx);
        float nxt = mx + __logf(ss) + em;
        if (mt && act) alpha = nxt;
    }
    float fv = act ? (alpha + end_trans[j]) : -1e30f;
    float mx = fv;
    for (int off = 32; off; off >>= 1) mx = fmaxf(mx, __shfl_xor(mx, off));
    float ss = act ? __expf(fv - mx) : 0.f;
    for (int off = 32; off; off >>= 1) ss += __shfl_xor(ss, off);
    float logZ = mx + __logf(ss);
    if (lane == 0) atomicAdd(out, (logZ - sc) * (1.0f/BATCH));
}

extern "C" void kernel_launch(void* const* d_in, const int* in_sizes, int n_in,
                              void* d_out, int out_size, void* d_ws, size_t ws_size,
                              hipStream_t stream) {
    const int*   sentence    = (const int*)  d_in[0];
    const int*   tags        = (const int*)  d_in[1];
    const float* embed       = (const float*)d_in[2];
    const float* wih_f       = (const float*)d_in[3];
    const float* whh_f       = (const float*)d_in[4];
    const float* bih_f       = (const float*)d_in[5];
    const float* bhh_f       = (const float*)d_in[6];
    const float* wih_b       = (const float*)d_in[7];
    const float* whh_b       = (const float*)d_in[8];
    const float* bih_b       = (const float*)d_in[9];
    const float* bhh_b       = (const float*)d_in[10];
    const float* w_out       = (const float*)d_in[11];
    const float* b_out       = (const float*)d_in[12];
    const float* start_trans = (const float*)d_in[13];
    const float* end_trans   = (const float*)d_in[14];
    const float* trans       = (const float*)d_in[15];
    const int*   mask        = (const int*)  d_in[16];

    char* ws = (char*)d_ws;
    f16*   xg     = (f16*)ws;   ws += (size_t)MROWS*KP*2;      // 20.97 MB
    f16*   wpack  = (f16*)ws;   ws += (size_t)NB*KP*2;         // 1.31 MB
    float* bias2  = (float*)ws; ws += (size_t)NB*4;            // 8 KB
    f16*   whhp3  = (f16*)ws;   ws += (size_t)1024*512*2;      // 1.05 MB
    f16*   xp5    = (f16*)ws;   ws += (size_t)MROWS*NB*2;      // 134.2 MB
    f16*   hcat   = (f16*)ws;   ws += (size_t)MROWS*512*2;     // 33.55 MB
    float* emis   = (float*)ws; ws += (size_t)MROWS*TAGS*4;    // 1.18 MB

    hipLaunchKernelGGL(k_pack_wih, dim3(NB), dim3(64), 0, stream,
                       wih_f, wih_b, bih_f, bhh_f, bih_b, bhh_b, wpack, bias2);
    hipLaunchKernelGGL(k_pack_whh3, dim3(256), dim3(256), 0, stream, whh_f, whh_b, whhp3);
    hipLaunchKernelGGL(k_gather, dim3(MROWS), dim3(64), 0, stream, sentence, embed, xg);
    hipLaunchKernelGGL(k_gemm_xproj, dim3(256,16), dim3(256), 0, stream, xg, wpack, bias2, xp5);
    hipLaunchKernelGGL(k_recur, dim3(128), dim3(256), 0, stream, xp5, whhp3, hcat);
    hipLaunchKernelGGL(k_emis, dim3(MROWS/4), dim3(256), 0, stream, hcat, w_out, b_out, emis);
    hipMemsetAsync(d_out, 0, sizeof(float), stream);
    hipLaunchKernelGGL(k_crf, dim3(BATCH/4), dim3(256), 0, stream,
                       emis, tags, mask, start_trans, end_trans, trans, (float*)d_out);
}

// Round 6
// 1267.589 us; speedup vs baseline: 5.6598x; 1.2882x over previous
//
#include <hip/hip_runtime.h>
#include <hip/hip_bf16.h>
#include <stdint.h>

#define EDIM 300
#define KP   320      // padded E for MFMA K-loop
#define HDIM 256
#define G4H  1024
#define NB   2048     // both directions' gates
#define TAGS 9
#define BATCH 64
#define SEQ  512
#define MROWS (SEQ*BATCH)   // 32768

typedef _Float16 f16;
typedef _Float16 half2_t __attribute__((ext_vector_type(2)));
typedef _Float16 half8_t __attribute__((ext_vector_type(8)));
typedef float    floatx4 __attribute__((ext_vector_type(4)));
typedef uint32_t u32x4   __attribute__((ext_vector_type(4)));

__device__ __forceinline__ float fast_sigmoid(float x) {
    return __builtin_amdgcn_rcpf(1.f + __expf(-x));
}
__device__ __forceinline__ float fast_tanh(float x) {
    // 1 - 2/(e^{2x}+1); exact at +-inf via rcp(inf)=0
    return 1.f - 2.f*__builtin_amdgcn_rcpf(__expf(2.f*x) + 1.f);
}

// ---- pack input-projection weights [n<1024: wih_f | n>=1024: wih_b], K padded to 320, + fused bias
__global__ void k_pack_wih(const float* __restrict__ wih_f, const float* __restrict__ wih_b,
                           const float* __restrict__ bih_f, const float* __restrict__ bhh_f,
                           const float* __restrict__ bih_b, const float* __restrict__ bhh_b,
                           f16* __restrict__ wpack, float* __restrict__ bias2) {
    int n = blockIdx.x;
    const float* src = (n < G4H) ? (wih_f + (long)n*EDIM) : (wih_b + (long)(n-G4H)*EDIM);
    for (int k = threadIdx.x; k < KP; k += 64)
        wpack[(long)n*KP + k] = (k < EDIM) ? (f16)src[k] : (f16)0.f;
    if (threadIdx.x == 0)
        bias2[n] = (n < G4H) ? (bih_f[n] + bhh_f[n]) : (bih_b[n-G4H] + bhh_b[n-G4H]);
}

// ---- pack recurrent weights into MFMA A-fragment layout for the 4-wave k_recur:
// frag f = ((dir*4 + w)*16 + fr)*8 + kf ; per frag: 64 lanes x 8 f16.
// A[row][k]: row = lane&15, k = (lane>>4)*8 + j.
// gate row = (fr>>2)*256 + w*64 + (fr&3)*16 + (lane&15); k = kf*32 + (lane>>4)*8 + j.
__global__ void k_pack_whh3(const float* __restrict__ whh_f, const float* __restrict__ whh_b,
                            f16* __restrict__ whhp3) {
    int idx = blockIdx.x*256 + threadIdx.x;   // 65536 = 2*4*16*8*64
    int lane = idx & 63;
    int kf = (idx >> 6) & 7;
    int fr = (idx >> 9) & 15;
    int w  = (idx >> 13) & 3;
    int dir = idx >> 15;
    const float* whh = dir ? whh_b : whh_f;
    int grow = (fr >> 2)*256 + w*64 + (fr & 3)*16 + (lane & 15);
    int k0 = kf*32 + (lane >> 4)*8;
    const float* src = whh + (long)grow*HDIM + k0;
    f16 tmp[8];
    #pragma unroll
    for (int j = 0; j < 8; ++j) tmp[j] = (f16)src[j];
    *(uint4*)(whhp3 + (size_t)idx*8) = *(uint4*)tmp;
}

// ---- embedding gather, f16, row m = t*64+b, padded to KP
__global__ void k_gather(const int* __restrict__ sentence, const float* __restrict__ embed,
                         f16* __restrict__ xg) {
    int m = blockIdx.x;
    int t = m >> 6, b = m & 63;
    int tok = sentence[b*SEQ + t];
    const float* row = embed + (long)tok*EDIM;
    for (int e = threadIdx.x; e < KP; e += 64)
        xg[(long)m*KP + e] = (e < EDIM) ? (f16)row[e] : (f16)0.f;
}

// ---- xp5 GEMM, M=32768 N=2048 K=320; epilogue writes x-preacts so that unit u's
// four gates (i,f,g,o) are adjacent:
// xp5[ ((dir*64 + b)*512 + s)*1024 + u*4 + gate ],  s = dir ? SEQ-1-t : t,
// where col = dir*1024 + gate*256 + u (u = 0..255).
__launch_bounds__(256)
__global__ void k_gemm_xproj(const f16* __restrict__ xg, const f16* __restrict__ wpack,
                             const float* __restrict__ bias2, f16* __restrict__ xp5) {
    __shared__ __align__(16) f16 As[128*40];
    __shared__ __align__(16) f16 Bs[128*40];
    int tid = threadIdx.x;
    int bm = blockIdx.x, bn = blockIdx.y;
    int wid = tid >> 6, lane = tid & 63;
    int waveM = wid & 1, waveN = wid >> 1;
    int quad = lane >> 4, mlo = lane & 15;
    floatx4 acc[4][4] = {};
    for (int k0 = 0; k0 < KP; k0 += 32) {
        for (int it = 0; it < 2; ++it) {
            int c = tid + it*256;
            int row = c >> 2, ko = (c & 3)*8;
            *(uint4*)(&As[row*40 + ko]) = *(const uint4*)(&xg[(long)(bm*128+row)*KP + k0 + ko]);
            *(uint4*)(&Bs[row*40 + ko]) = *(const uint4*)(&wpack[(long)(bn*128+row)*KP + k0 + ko]);
        }
        __syncthreads();
        half8_t af[4], bf[4];
        #pragma unroll
        for (int i = 0; i < 4; ++i)
            af[i] = *(const half8_t*)(&As[(waveM*64 + i*16 + mlo)*40 + quad*8]);
        #pragma unroll
        for (int j = 0; j < 4; ++j)
            bf[j] = *(const half8_t*)(&Bs[(waveN*64 + j*16 + mlo)*40 + quad*8]);
        #pragma unroll
        for (int i = 0; i < 4; ++i)
            #pragma unroll
            for (int j = 0; j < 4; ++j)
                acc[i][j] = __builtin_amdgcn_mfma_f32_16x16x32_f16(af[i], bf[j], acc[i][j], 0, 0, 0);
        __syncthreads();
    }
    #pragma unroll
    for (int i = 0; i < 4; ++i)
        #pragma unroll
        for (int j = 0; j < 4; ++j) {
            int col = bn*128 + waveN*64 + j*16 + mlo;   // 0..2047
            float bv = bias2[col];
            int dir = col >> 10, grow = col & 1023;
            int gate = grow >> 8, u = grow & 255;
            int rowp = u*4 + gate;
            #pragma unroll
            for (int r = 0; r < 4; ++r) {
                int row = bm*128 + waveM*64 + i*16 + quad*4 + r;
                int t = row >> 6, bb = row & 63;
                int s = dir ? (SEQ-1-t) : t;
                xp5[((size_t)(dir*64 + bb)*512 + s)*1024 + rowp] = (f16)(acc[i][j][r] + bv);
            }
        }
}

// ---- LSTM recurrence on MFMA, one WG per (dir,batch): 128 WGs, 256 threads = 4 waves,
// 1 wave/SIMD, __launch_bounds__(256,1). Wave w owns gate rows {gate*256+w*64 ..+64}
// for all 4 gates: 16 frags x 8 kf = 128 MFMA/step/wave (validated R5, absmax 0).
// v6: MFMA issued via inline asm with pinned register classes so W is consumed
// IN PLACE (no AGPR->VGPR shuttle, which R5's counters exposed as ~1000+ VALU
// cyc/step): 64 frags in AGPR ("a" operands, exactly 256 AGPRs), 32 frags in VGPR
// ("v"), 32 frags in LDS (128 KB). acc stays "+v" (cell reads it directly); kf=0
// uses an untied "=&v" form with a once-zeroed C tuple (no per-step acc init).
// Cell phase: col-0 lanes dump acc to wave-local gbuf, each of 64 lanes updates one
// unit. One coalesced uint2/lane/step x-preact from xp5, prefetched one step ahead.
// One raw lgkmcnt(0)+s_barrier per step (global prefetch stays in flight).
#define AFRAG 64
#define VFRAG 32
#define LFRAG 32    // 64+32+32 = 128 frags/wave
__launch_bounds__(256, 1)
__global__ void k_recur(const f16* __restrict__ xp5, const f16* __restrict__ whhp3,
                        f16* __restrict__ hcat) {
    __shared__ __align__(16) uint4 ldsW[4*LFRAG*64];   // 128 KB: [w][f-96][lane]
    __shared__ __align__(16) float gbuf[4][16][16];    // 4 KB: [w][fr][lq*4+r] (col 0)
    __shared__ __align__(16) f16 hbuf[2][256];         // 1 KB, double buffered
    int dir = blockIdx.x & 1, b = blockIdx.x >> 1;
    int tid = threadIdx.x, w = tid >> 6, lane = tid & 63;
    int q = lane >> 4;          // k-group / row-quad
    int v = lane;               // unit owned in cell phase: u256 = w*64 + v

    // ---- stationary W fragments: 0..63 -> AGPR, 64..95 -> VGPR, 96..127 -> LDS
    const f16* wbase = whhp3 + (size_t)(dir*4 + w)*131072;
    u32x4 wa[AFRAG], wv[VFRAG];
    #pragma unroll
    for (int f = 0; f < AFRAG; ++f)
        wa[f] = *(const u32x4*)(wbase + ((size_t)f*64 + lane)*8);
    #pragma unroll
    for (int f = 0; f < VFRAG; ++f)
        wv[f] = *(const u32x4*)(wbase + ((size_t)(AFRAG + f)*64 + lane)*8);
    #pragma unroll
    for (int f2 = 0; f2 < LFRAG; ++f2)
        ldsW[(w*LFRAG + f2)*64 + lane] =
            *(const uint4*)(wbase + ((size_t)(AFRAG + VFRAG + f2)*64 + lane)*8);

    if (tid < 128) ((uint32_t*)&hbuf[0][0])[tid] = 0u;

    // per-lane x source: 4 gate preacts of unit (w*64+v), linear in s
    const f16* xs = xp5 + ((size_t)(dir*64 + b)*512)*1024 + (w*64 + v)*4;
    uint2 xw = *(const uint2*)xs;

    floatx4 zc = {0.f, 0.f, 0.f, 0.f};   // shared zero C-operand, zeroed once
    float cc = 0.f;
    __syncthreads();

    for (int s = 0; s < SEQ; ++s) {
        int t = dir ? (SEQ-1-s) : s;
        // prefetch next step's x (stays in flight across the raw barrier)
        int sp = (s+1 < SEQ) ? s+1 : s;
        uint2 xn = *(const uint2*)(xs + (size_t)sp*1024);
        // ---- 128 MFMA over K=256, constraint-pinned operands
        floatx4 acc[16];
        const f16* hp = &hbuf[s & 1][0];
        #pragma unroll
        for (int kf = 0; kf < 8; ++kf) {
            half8_t bf = *(const half8_t*)(hp + kf*32 + q*8);
            #pragma unroll
            for (int fr = 0; fr < 16; ++fr) {
                const int f = fr*8 + kf;
                if (kf == 0) {
                    if (f < AFRAG)
                        asm("v_mfma_f32_16x16x32_f16 %0, %1, %2, %3"
                            : "=&v"(acc[fr]) : "a"(wa[f]), "v"(bf), "v"(zc));
                    else if (f < AFRAG + VFRAG)
                        asm("v_mfma_f32_16x16x32_f16 %0, %1, %2, %3"
                            : "=&v"(acc[fr]) : "v"(wv[f - AFRAG]), "v"(bf), "v"(zc));
                    else {
                        half8_t af = *(const half8_t*)((const f16*)&ldsW[(w*LFRAG + (f - AFRAG - VFRAG))*64 + lane]);
                        asm("v_mfma_f32_16x16x32_f16 %0, %1, %2, %3"
                            : "=&v"(acc[fr]) : "v"(af), "v"(bf), "v"(zc));
                    }
                } else {
                    if (f < AFRAG)
                        asm("v_mfma_f32_16x16x32_f16 %0, %1, %2, %0"
                            : "+v"(acc[fr]) : "a"(wa[f]), "v"(bf));
                    else if (f < AFRAG + VFRAG)
                        asm("v_mfma_f32_16x16x32_f16 %0, %1, %2, %0"
                            : "+v"(acc[fr]) : "v"(wv[f - AFRAG]), "v"(bf));
                    else {
                        half8_t af = *(const half8_t*)((const f16*)&ldsW[(w*LFRAG + (f - AFRAG - VFRAG))*64 + lane]);
                        asm("v_mfma_f32_16x16x32_f16 %0, %1, %2, %0"
                            : "+v"(acc[fr]) : "v"(af), "v"(bf));
                    }
                }
            }
        }
        // ---- col-0 lanes dump gates to wave-local gbuf (no cross-wave use -> no barrier)
        if ((lane & 15) == 0) {
            #pragma unroll
            for (int fr = 0; fr < 16; ++fr)
                *(floatx4*)&gbuf[w][fr][q*4] = acc[fr];
        }
        // ---- each lane updates one unit: u256 = w*64 + v
        {
            int sub = v >> 4, rr = v & 15;
            half2_t xif = __builtin_bit_cast(half2_t, xw.x);
            half2_t xgo = __builtin_bit_cast(half2_t, xw.y);
            float pi = gbuf[w][0  + sub][rr] + (float)xif[0];
            float pf = gbuf[w][4  + sub][rr] + (float)xif[1];
            float pg = gbuf[w][8  + sub][rr] + (float)xgo[0];
            float po = gbuf[w][12 + sub][rr] + (float)xgo[1];
            float si = fast_sigmoid(pi), sf = fast_sigmoid(pf);
            float tg = fast_tanh(pg),   so = fast_sigmoid(po);
            cc = __builtin_fmaf(sf, cc, si*tg);
            f16 hh = (f16)(so * fast_tanh(cc));
            hbuf[(s+1) & 1][w*64 + v] = hh;
            hcat[((size_t)t*64 + b)*512 + dir*HDIM + w*64 + v] = hh;
        }
        xw = xn;
        asm volatile("s_waitcnt lgkmcnt(0)" ::: "memory");
        __builtin_amdgcn_s_barrier();
        asm volatile("" ::: "memory");
    }
}

// ---- emissions: one wave per (t,b) row; lanes split K=512; 9 shuffle-reduced dots
__launch_bounds__(256)
__global__ void k_emis(const f16* __restrict__ hcat, const float* __restrict__ w_out,
                       const float* __restrict__ b_out, float* __restrict__ emis) {
    int r = blockIdx.x*4 + (threadIdx.x >> 6);
    int lane = threadIdx.x & 63;
    float hv[8];
    #pragma unroll
    for (int i = 0; i < 8; ++i) hv[i] = (float)hcat[(long)r*512 + lane + i*64];
    for (int tag = 0; tag < TAGS; ++tag) {
        float acc = 0.f;
        #pragma unroll
        for (int i = 0; i < 8; ++i) acc += hv[i]*w_out[tag*512 + lane + i*64];
        for (int off = 32; off; off >>= 1) acc += __shfl_xor(acc, off);
        if (lane == 0) emis[(long)r*TAGS + tag] = acc + b_out[tag];
    }
}

// ---- CRF: one wave per batch row. Gold score (lane-parallel over t) + forward logZ
__launch_bounds__(256)
__global__ void k_crf(const float* __restrict__ emis, const int* __restrict__ tags,
                      const int* __restrict__ mask, const float* __restrict__ start_trans,
                      const float* __restrict__ end_trans, const float* __restrict__ trans,
                      float* __restrict__ out) {
    int b = blockIdx.x*4 + (threadIdx.x >> 6);
    int lane = threadIdx.x & 63;
    int len = 0;
    #pragma unroll
    for (int i = 0; i < 8; ++i) len += mask[b*SEQ + lane + i*64];
    for (int off = 32; off; off >>= 1) len += __shfl_xor(len, off);
    float sc = 0.f;
    for (int i = 0; i < 8; ++i) {
        int t = 1 + lane + i*64;
        if (t < SEQ && mask[b*SEQ + t]) {
            int tp = tags[b*SEQ + t - 1], tc = tags[b*SEQ + t];
            sc += trans[tp*TAGS + tc] + emis[(long)(t*64 + b)*TAGS + tc];
        }
    }
    for (int off = 32; off; off >>= 1) sc += __shfl_xor(sc, off);
    int tag0 = tags[b*SEQ];
    sc += start_trans[tag0] + emis[(long)b*TAGS + tag0];
    sc += end_trans[tags[b*SEQ + len - 1]];
    bool act = lane < TAGS;
    int j = act ? lane : 0;
    float tcol[TAGS];
    #pragma unroll
    for (int i = 0; i < TAGS; ++i) tcol[i] = trans[i*TAGS + j];
    float alpha = act ? (start_trans[j] + emis[(long)b*TAGS + j]) : -1e30f;
    for (int t = 1; t < SEQ; ++t) {
        int mt = mask[b*SEQ + t];
        float em = emis[(long)(t*64 + b)*TAGS + j];
        float v[TAGS], mx = -1e30f;
        #pragma unroll
        for (int i = 0; i < TAGS; ++i) { v[i] = __shfl(alpha, i) + tcol[i]; mx = fmaxf(mx, v[i]); }
        float ss = 0.f;
        #pragma unroll
        for (int i = 0; i < TAGS; ++i) ss += __expf(v[i] - mx);
        float nxt = mx + __logf(ss) + em;
        if (mt && act) alpha = nxt;
    }
    float fv = act ? (alpha + end_trans[j]) : -1e30f;
    float mx = fv;
    for (int off = 32; off; off >>= 1) mx = fmaxf(mx, __shfl_xor(mx, off));
    float ss = act ? __expf(fv - mx) : 0.f;
    for (int off = 32; off; off >>= 1) ss += __shfl_xor(ss, off);
    float logZ = mx + __logf(ss);
    if (lane == 0) atomicAdd(out, (logZ - sc) * (1.0f/BATCH));
}

extern "C" void kernel_launch(void* const* d_in, const int* in_sizes, int n_in,
                              void* d_out, int out_size, void* d_ws, size_t ws_size,
                              hipStream_t stream) {
    const int*   sentence    = (const int*)  d_in[0];
    const int*   tags        = (const int*)  d_in[1];
    const float* embed       = (const float*)d_in[2];
    const float* wih_f       = (const float*)d_in[3];
    const float* whh_f       = (const float*)d_in[4];
    const float* bih_f       = (const float*)d_in[5];
    const float* bhh_f       = (const float*)d_in[6];
    const float* wih_b       = (const float*)d_in[7];
    const float* whh_b       = (const float*)d_in[8];
    const float* bih_b       = (const float*)d_in[9];
    const float* bhh_b       = (const float*)d_in[10];
    const float* w_out       = (const float*)d_in[11];
    const float* b_out       = (const float*)d_in[12];
    const float* start_trans = (const float*)d_in[13];
    const float* end_trans   = (const float*)d_in[14];
    const float* trans       = (const float*)d_in[15];
    const int*   mask        = (const int*)  d_in[16];

    char* ws = (char*)d_ws;
    f16*   xg     = (f16*)ws;   ws += (size_t)MROWS*KP*2;      // 20.97 MB
    f16*   wpack  = (f16*)ws;   ws += (size_t)NB*KP*2;         // 1.31 MB
    float* bias2  = (float*)ws; ws += (size_t)NB*4;            // 8 KB
    f16*   whhp3  = (f16*)ws;   ws += (size_t)1024*512*2;      // 1.05 MB
    f16*   xp5    = (f16*)ws;   ws += (size_t)MROWS*NB*2;      // 134.2 MB
    f16*   hcat   = (f16*)ws;   ws += (size_t)MROWS*512*2;     // 33.55 MB
    float* emis   = (float*)ws; ws += (size_t)MROWS*TAGS*4;    // 1.18 MB

    hipLaunchKernelGGL(k_pack_wih, dim3(NB), dim3(64), 0, stream,
                       wih_f, wih_b, bih_f, bhh_f, bih_b, bhh_b, wpack, bias2);
    hipLaunchKernelGGL(k_pack_whh3, dim3(256), dim3(256), 0, stream, whh_f, whh_b, whhp3);
    hipLaunchKernelGGL(k_gather, dim3(MROWS), dim3(64), 0, stream, sentence, embed, xg);
    hipLaunchKernelGGL(k_gemm_xproj, dim3(256,16), dim3(256), 0, stream, xg, wpack, bias2, xp5);
    hipLaunchKernelGGL(k_recur, dim3(128), dim3(256), 0, stream, xp5, whhp3, hcat);
    hipLaunchKernelGGL(k_emis, dim3(MROWS/4), dim3(256), 0, stream, hcat, w_out, b_out, emis);
    hipMemsetAsync(d_out, 0, sizeof(float), stream);
    hipLaunchKernelGGL(k_crf, dim3(BATCH/4), dim3(256), 0, stream,
                       emis, tags, mask, start_trans, end_trans, trans, (float*)d_out);
}